// Round 4
// baseline (226.409 us; speedup 1.0000x reference)
//
#include <hip/hip_runtime.h>
#include <math.h>

// ---- problem constants ----
#define NCOL   114688      // P*PED = 224*512
#define NCOL4  28672       // NCOL/4
#define KTOT   384         // EMB
#define NCH    16          // k-chunks for the GEMV
#define KCH    24          // KTOT/NCH
#define NROWS  448         // B * 224
#define PED    512

typedef float v4f __attribute__((ext_vector_type(4)));

// ws layout (floats)
#define OFF_PART 0
#define OFF_AB   (NCH * 2 * NCOL)          // 3,670,016
#define OFF_BB   (OFF_AB + NROWS * 1024)   // 4,128,768
// total: 4,587,520 floats = 18.35 MB

// K1: partial GEMV  part[ch][b][col] = sum_{k in chunk} cond[b][k] * W[k][col]
__global__ __launch_bounds__(256) void k_gemv(const float* __restrict__ cond,
                                              const float* __restrict__ W,
                                              float* __restrict__ part) {
    const int col4 = blockIdx.x * 256 + threadIdx.x;   // [0, 28672)
    const int ch   = blockIdx.y;
    const int k0   = ch * KCH;
    __shared__ float cs[2 * KCH];
    if (threadIdx.x < 2 * KCH) {
        int b  = threadIdx.x / KCH;
        int kk = threadIdx.x - b * KCH;
        cs[threadIdx.x] = cond[b * KTOT + k0 + kk];
    }
    __syncthreads();
    const float4* __restrict__ W4 = (const float4*)W;
    float4 a0 = make_float4(0.f, 0.f, 0.f, 0.f);
    float4 a1 = make_float4(0.f, 0.f, 0.f, 0.f);
#pragma unroll 8
    for (int kk = 0; kk < KCH; ++kk) {
        float4 w = W4[(size_t)(k0 + kk) * NCOL4 + col4];
        float c0 = cs[kk];
        float c1 = cs[KCH + kk];
        a0.x = fmaf(c0, w.x, a0.x); a0.y = fmaf(c0, w.y, a0.y);
        a0.z = fmaf(c0, w.z, a0.z); a0.w = fmaf(c0, w.w, a0.w);
        a1.x = fmaf(c1, w.x, a1.x); a1.y = fmaf(c1, w.y, a1.y);
        a1.z = fmaf(c1, w.z, a1.z); a1.w = fmaf(c1, w.w, a1.w);
    }
    float4* p4 = (float4*)part;
    p4[((size_t)ch * 2 + 0) * NCOL4 + col4] = a0;
    p4[((size_t)ch * 2 + 1) * NCOL4 + col4] = a1;
}

__device__ __forceinline__ float gelu_erf(float x) {
    return 0.5f * x * (1.0f + erff(x * 0.70710678118654752440f));
}

// K2: fused reduce + dec1 + dec2 (+bias +scale). 2 rows per block, 224 blocks.
__global__ __launch_bounds__(256) void k_fused(const float* __restrict__ part,
                                               const float* __restrict__ bproj,
                                               const float* __restrict__ WA1,
                                               const float* __restrict__ bA1,
                                               const float* __restrict__ WA2,
                                               const float* __restrict__ bA2,
                                               const float* __restrict__ WB1,
                                               const float* __restrict__ bB1,
                                               const float* __restrict__ WB2,
                                               const float* __restrict__ bB2,
                                               const float* __restrict__ scales,
                                               float* __restrict__ Ab,
                                               float* __restrict__ Bb) {
    const int tid = threadIdx.x;
    const int y0  = blockIdx.x * 2;        // rows y0, y0+1 (same b: 224 even)
    const int b   = y0 / 224;
    const int p0  = y0 - b * 224;          // = l*7+t for row 0; row 1 is p0+1

    __shared__ float pe_s[2][512];
    __shared__ float hA_s[2][256];
    __shared__ float hB_s[2][256];

    // stage 0: reduce partials -> pe rows (float4 per thread)
    {
        const int r  = tid >> 7;
        const int c4 = tid & 127;
        const size_t colbase = (size_t)(p0 + r) * 128 + c4;
        const float4* __restrict__ p4 = (const float4*)part;
        float4 s = ((const float4*)bproj)[colbase];
#pragma unroll
        for (int ch = 0; ch < NCH; ++ch) {
            float4 v = p4[((size_t)ch * 2 + b) * NCOL4 + colbase];
            s.x += v.x; s.y += v.y; s.z += v.z; s.w += v.w;
        }
        ((float4*)pe_s)[tid] = s;
    }
    __syncthreads();

    // stage 1: dec1 (448x512 @ 512x256), j = tid
    {
        const int j = tid;
        float a0 = 0.f, a1 = 0.f, c0 = 0.f, c1 = 0.f;
#pragma unroll 8
        for (int k = 0; k < 512; ++k) {
            float wa = WA1[k * 256 + j];
            float wb = WB1[k * 256 + j];
            float q0 = pe_s[0][k];
            float q1 = pe_s[1][k];
            a0 = fmaf(q0, wa, a0); a1 = fmaf(q1, wa, a1);
            c0 = fmaf(q0, wb, c0); c1 = fmaf(q1, wb, c1);
        }
        const float ba = bA1[j], bb = bB1[j];
        hA_s[0][j] = gelu_erf(a0 + ba);
        hA_s[1][j] = gelu_erf(a1 + ba);
        hB_s[0][j] = gelu_erf(c0 + bb);
        hB_s[1][j] = gelu_erf(c1 + bb);
    }
    __syncthreads();

    // stage 2: dec2 (448x256 @ 256x1024), thread owns float4 column j4 = tid
    {
        float4 aA0 = make_float4(0.f, 0.f, 0.f, 0.f);
        float4 aA1 = make_float4(0.f, 0.f, 0.f, 0.f);
        float4 aB0 = make_float4(0.f, 0.f, 0.f, 0.f);
        float4 aB1 = make_float4(0.f, 0.f, 0.f, 0.f);
        const float4* __restrict__ WA2_4 = (const float4*)WA2;
        const float4* __restrict__ WB2_4 = (const float4*)WB2;
#pragma unroll 4
        for (int k = 0; k < 256; ++k) {
            float4 wa = WA2_4[k * 256 + tid];
            float4 wb = WB2_4[k * 256 + tid];
            float hA0 = hA_s[0][k], hA1 = hA_s[1][k];
            float hB0 = hB_s[0][k], hB1 = hB_s[1][k];
            aA0.x = fmaf(hA0, wa.x, aA0.x); aA0.y = fmaf(hA0, wa.y, aA0.y);
            aA0.z = fmaf(hA0, wa.z, aA0.z); aA0.w = fmaf(hA0, wa.w, aA0.w);
            aA1.x = fmaf(hA1, wa.x, aA1.x); aA1.y = fmaf(hA1, wa.y, aA1.y);
            aA1.z = fmaf(hA1, wa.z, aA1.z); aA1.w = fmaf(hA1, wa.w, aA1.w);
            aB0.x = fmaf(hB0, wb.x, aB0.x); aB0.y = fmaf(hB0, wb.y, aB0.y);
            aB0.z = fmaf(hB0, wb.z, aB0.z); aB0.w = fmaf(hB0, wb.w, aB0.w);
            aB1.x = fmaf(hB1, wb.x, aB1.x); aB1.y = fmaf(hB1, wb.y, aB1.y);
            aB1.z = fmaf(hB1, wb.z, aB1.z); aB1.w = fmaf(hB1, wb.w, aB1.w);
        }
        const float4 ba = ((const float4*)bA2)[tid];
        const float4 bb = ((const float4*)bB2)[tid];
        const float scA0 = scales[p0 * 2],       scB0 = scales[p0 * 2 + 1];
        const float scA1 = scales[(p0 + 1) * 2], scB1 = scales[(p0 + 1) * 2 + 1];
        float4* __restrict__ Ab4 = (float4*)Ab;
        float4* __restrict__ Bb4 = (float4*)Bb;
        float4 o;
        o.x = (aA0.x + ba.x) * scA0; o.y = (aA0.y + ba.y) * scA0;
        o.z = (aA0.z + ba.z) * scA0; o.w = (aA0.w + ba.w) * scA0;
        Ab4[(size_t)y0 * 256 + tid] = o;
        o.x = (aA1.x + ba.x) * scA1; o.y = (aA1.y + ba.y) * scA1;
        o.z = (aA1.z + ba.z) * scA1; o.w = (aA1.w + ba.w) * scA1;
        Ab4[(size_t)(y0 + 1) * 256 + tid] = o;
        o.x = (aB0.x + bb.x) * scB0; o.y = (aB0.y + bb.y) * scB0;
        o.z = (aB0.z + bb.z) * scB0; o.w = (aB0.w + bb.w) * scB0;
        Bb4[(size_t)y0 * 256 + tid] = o;
        o.x = (aB1.x + bb.x) * scB1; o.y = (aB1.y + bb.y) * scB1;
        o.z = (aB1.z + bb.z) * scB1; o.w = (aB1.w + bb.w) * scB1;
        Bb4[(size_t)(y0 + 1) * 256 + tid] = o;
    }
}

// K3: scatter/tile into the output (pure copy; scales already applied).
template <bool NT>
__global__ __launch_bounds__(256) void k_scatter(const float* __restrict__ Ab,
                                                 const float* __restrict__ Bb,
                                                 float* __restrict__ out) {
    const int y  = blockIdx.y;
    const int t  = y % 7;
    const int lb = y / 7;          // b*32 + l
    const int l  = lb & 31;
    const int b  = lb >> 5;

    int in_d = (t == 6) ? 11008 : 4096;
    int out_d, poff;
    switch (t) {
        case 0:  out_d = 4096;  poff = 0;      break;
        case 1:  out_d = 1024;  poff = 131072; break;
        case 2:  out_d = 1024;  poff = 212992; break;
        case 3:  out_d = 4096;  poff = 294912; break;
        case 4:  out_d = 11008; poff = 425984; break;
        case 5:  out_d = 11008; poff = 667648; break;
        default: out_d = 4096;  poff = 909312; break;
    }
    __shared__ v4f As4[256];
    __shared__ v4f Bs4[256];
    const v4f* __restrict__ Arow4 = (const v4f*)Ab + (size_t)y * 256;
    const v4f* __restrict__ Brow4 = (const v4f*)Bb + (size_t)y * 256;
    As4[threadIdx.x] = Arow4[threadIdx.x];
    Bs4[threadIdx.x] = Brow4[threadIdx.x];
    __syncthreads();

    const size_t base4 = ((size_t)b * 36831232u + (size_t)l * 1150976u + (size_t)poff) >> 2;
    v4f* __restrict__ dst = (v4f*)out + base4;

    const int nA4    = in_d << 2;               // float4 count of A piece
    const int nAll4  = (in_d + out_d) << 2;     // total float4 count of piece
    const int stride = gridDim.x * 256;
    const bool p2 = (in_d == 4096);

    for (int e4 = blockIdx.x * 256 + threadIdx.x; e4 < nAll4; e4 += stride) {
        v4f v;
        if (e4 < nA4) {
            int r = p2 ? (e4 >> 10)
                       : (int)(((unsigned)(e4 >> 6) * 1525u) >> 16);  // /43 magic, exact for x<1680
            v = As4[(r << 4) | (e4 & 15)];
        } else {
            int f = e4 - nA4;
            v = Bs4[(((f >> 2) & 63) << 2) | (f & 3)];
        }
        if (NT) __builtin_nontemporal_store(v, &dst[e4]);
        else    dst[e4] = v;
    }
}

extern "C" void kernel_launch(void* const* d_in, const int* in_sizes, int n_in,
                              void* d_out, int out_size, void* d_ws, size_t ws_size,
                              hipStream_t stream) {
    const float* cond   = (const float*)d_in[0];
    const float* Wp     = (const float*)d_in[1];
    const float* bproj  = (const float*)d_in[2];
    const float* WA1    = (const float*)d_in[3];
    const float* bA1    = (const float*)d_in[4];
    const float* WA2    = (const float*)d_in[5];
    const float* bA2    = (const float*)d_in[6];
    const float* WB1    = (const float*)d_in[7];
    const float* bB1    = (const float*)d_in[8];
    const float* WB2    = (const float*)d_in[9];
    const float* bB2    = (const float*)d_in[10];
    const float* scales = (const float*)d_in[11];
    float* out = (float*)d_out;
    float* ws  = (float*)d_ws;

    float* part = ws + OFF_PART;
    float* Ab   = ws + OFF_AB;
    float* Bb   = ws + OFF_BB;

    hipLaunchKernelGGL(k_gemv,  dim3(112, NCH), dim3(256), 0, stream, cond, Wp, part);
    hipLaunchKernelGGL(k_fused, dim3(224),      dim3(256), 0, stream,
                       part, bproj, WA1, bA1, WA2, bA2, WB1, bB1, WB2, bB2, scales, Ab, Bb);
    // Main scatter (identical to round 2)
    hipLaunchKernelGGL((k_scatter<false>), dim3(16, 448), dim3(256), 0, stream, Ab, Bb, out);
    // DIAGNOSTIC: duplicate scatter with nontemporal stores, writes identical
    // bytes. dur_us - 208 == cost of one full 295 MB tiled write pass (nt).
    hipLaunchKernelGGL((k_scatter<true>),  dim3(16, 448), dim3(256), 0, stream, Ab, Bb, out);
}

// Round 5
// 146.045 us; speedup vs baseline: 1.5503x; 1.5503x over previous
//
#include <hip/hip_runtime.h>
#include <math.h>

typedef float v4f __attribute__((ext_vector_type(4)));

#define NCOL4 28672        // W_proj row length in float4 (114688/4)

__device__ __forceinline__ float gelu_erf(float x) {
    return 0.5f * x * (1.0f + erff(x * 0.70710678118654752440f));
}

// One block = one (b, l, t) output tile, end to end.
// 448 blocks x 512 threads. Block y: p = y>>1 (= l*7+t), b = y&1, so the two
// blocks sharing a W_proj column slice are adjacent in dispatch order (L2/L3 hit).
__global__ __launch_bounds__(512) void k_mega(const float* __restrict__ cond,
                                              const float* __restrict__ W,
                                              const float* __restrict__ bproj,
                                              const float* __restrict__ WA1,
                                              const float* __restrict__ bA1,
                                              const float* __restrict__ WA2,
                                              const float* __restrict__ bA2,
                                              const float* __restrict__ WB1,
                                              const float* __restrict__ bB1,
                                              const float* __restrict__ WB2,
                                              const float* __restrict__ bB2,
                                              const float* __restrict__ scales,
                                              float* __restrict__ out) {
    const int tid = threadIdx.x;
    const int y   = blockIdx.x;      // [0,448)
    const int p   = y >> 1;          // [0,224) = l*7 + t
    const int b   = y & 1;
    const int t   = p % 7;
    const int l   = p / 7;

    __shared__ float cs[384];        // cond row
    __shared__ v4f   buf4[512];      // GEMV k-reduce, later scaled Ab|Bb staging
    __shared__ float pe_s[512];
    __shared__ float h_s[2][256];

    if (tid < 384) cs[tid] = cond[b * 384 + tid];
    __syncthreads();

    // ---- stage 1: pe = cond[b] @ W[:, p*512 .. p*512+512) + bproj slice ----
    {
        const int kres = tid >> 7;           // k residue 0..3 (wave-uniform)
        const int c4   = tid & 127;          // float4 column within slice
        const v4f* __restrict__ Wp4 =
            (const v4f*)W + (size_t)kres * NCOL4 + (size_t)p * 128 + c4;
        v4f acc = {0.f, 0.f, 0.f, 0.f};
#pragma unroll 4
        for (int i = 0; i < 96; ++i) {       // k = 4*i + kres
            v4f w = Wp4[(size_t)i * (4 * NCOL4)];
            acc += w * cs[4 * i + kres];
        }
        buf4[tid] = acc;
    }
    __syncthreads();
    if (tid < 128) {
        v4f s = buf4[tid] + buf4[tid + 128] + buf4[tid + 256] + buf4[tid + 384];
        s += ((const v4f*)bproj)[(size_t)p * 128 + tid];
        ((v4f*)pe_s)[tid] = s;
    }
    __syncthreads();

    // ---- stage 2: dec1 — h = gelu(pe @ W1 + b1), both paths in parallel ----
    {
        const int path = tid >> 8;           // 0 = A, 1 = B (wave-uniform)
        const int j    = tid & 255;
        const float* __restrict__ W1 = path ? WB1 : WA1;
        const float* __restrict__ b1 = path ? bB1 : bA1;
        float acc = 0.f;
#pragma unroll 8
        for (int k = 0; k < 512; ++k)
            acc = fmaf(pe_s[k], W1[k * 256 + j], acc);
        h_s[path][j] = gelu_erf(acc + b1[j]);
    }
    __syncthreads();

    // ---- stage 3: dec2 — row = (h @ W2 + b2) * scale, staged into buf4 ----
    {
        const int path = tid >> 8;
        const int j4   = tid & 255;          // float4 column of the 1024-row
        const v4f* __restrict__ W2 = (const v4f*)(path ? WB2 : WA2);
        const v4f  b2 = ((const v4f*)(path ? bB2 : bA2))[j4];
        const float sc = scales[p * 2 + path];
        const float* __restrict__ hp = h_s[path];
        v4f acc = {0.f, 0.f, 0.f, 0.f};
#pragma unroll 4
        for (int k = 0; k < 256; ++k)
            acc += hp[k] * W2[k * 256 + j4];
        buf4[tid] = (acc + b2) * sc;         // [0..255]=A row, [256..511]=B row
    }
    __syncthreads();

    // ---- stage 4: scatter tile with nontemporal stores ----
    int in_d = (t == 6) ? 11008 : 4096;
    int out_d, poff;
    switch (t) {
        case 0:  out_d = 4096;  poff = 0;      break;
        case 1:  out_d = 1024;  poff = 131072; break;
        case 2:  out_d = 1024;  poff = 212992; break;
        case 3:  out_d = 4096;  poff = 294912; break;
        case 4:  out_d = 11008; poff = 425984; break;
        case 5:  out_d = 11008; poff = 667648; break;
        default: out_d = 4096;  poff = 909312; break;
    }
    const size_t base4 = ((size_t)b * 36831232u + (size_t)l * 1150976u + (size_t)poff) >> 2;
    v4f* __restrict__ dst = (v4f*)out + base4;

    const int nA4   = in_d << 2;             // float4 count of A piece (16 x in_d)
    const int nAll4 = (in_d + out_d) << 2;   // + B piece (out_d x 16)
    const bool p2   = (in_d == 4096);

    for (int e4 = tid; e4 < nAll4; e4 += 512) {
        v4f v;
        if (e4 < nA4) {
            // A[r][j] = Arow[r*16 + (j/4)%16]; r = e4 / (in_d/4)
            int r = p2 ? (e4 >> 10)
                       : (int)(((unsigned)(e4 >> 6) * 1525u) >> 16);  // /43, exact x<1680
            v = buf4[(r << 4) | (e4 & 15)];
        } else {
            // B[i][j] = Brow[(i%64)*4 + j4]
            int f = e4 - nA4;
            v = buf4[256 + ((((f >> 2) & 63) << 2) | (f & 3))];
        }
        __builtin_nontemporal_store(v, &dst[e4]);
    }
}

extern "C" void kernel_launch(void* const* d_in, const int* in_sizes, int n_in,
                              void* d_out, int out_size, void* d_ws, size_t ws_size,
                              hipStream_t stream) {
    const float* cond   = (const float*)d_in[0];
    const float* Wp     = (const float*)d_in[1];
    const float* bproj  = (const float*)d_in[2];
    const float* WA1    = (const float*)d_in[3];
    const float* bA1    = (const float*)d_in[4];
    const float* WA2    = (const float*)d_in[5];
    const float* bA2    = (const float*)d_in[6];
    const float* WB1    = (const float*)d_in[7];
    const float* bB1    = (const float*)d_in[8];
    const float* WB2    = (const float*)d_in[9];
    const float* bB2    = (const float*)d_in[10];
    const float* scales = (const float*)d_in[11];
    float* out = (float*)d_out;

    hipLaunchKernelGGL(k_mega, dim3(448), dim3(512), 0, stream,
                       cond, Wp, bproj, WA1, bA1, WA2, bA2, WB1, bB1, WB2, bB2,
                       scales, out);
}

// Round 6
// 128.049 us; speedup vs baseline: 1.7681x; 1.1405x over previous
//
#include <hip/hip_runtime.h>
#include <math.h>

typedef float v4f __attribute__((ext_vector_type(4)));

#define NCOL4  28672       // W_proj row length in float4 (114688/4)
#define LAYER4 287744      // floats-per-layer / 4 (1150976/4) = 281*1024

// ws layout (floats)
#define OFF_PE   0                       // pe: 448 rows x 512
#define OFF_ROWS (448 * 512)             // rows: 896 x 1024 (A,B interleaved by path)
// total: 229376 + 917504 = 1,146,880 floats = 4.6 MB

__device__ __forceinline__ float gelu_erf(float x) {
    return 0.5f * x * (1.0f + erff(x * 0.70710678118654752440f));
}

// K1: pe[(p*2+b)][512] = cond[b] @ W[:, p*512..+512) + bproj slice.
// 224 blocks (one per p), 512 threads, k-split 4 in-block. Reads W exactly once.
__global__ __launch_bounds__(512) void k_gemv(const float* __restrict__ cond,
                                              const float* __restrict__ W,
                                              const float* __restrict__ bproj,
                                              float* __restrict__ pe) {
    const int tid = threadIdx.x;
    const int p   = blockIdx.x;          // [0,224)

    __shared__ float cs[768];            // cond, both rows
    __shared__ v4f   red[1024];          // k-split reduce (16 KB)

    cs[tid] = cond[tid >= 384 ? tid : tid];   // tid<512 covers [0,512)
    if (tid < 256) cs[512 + tid] = cond[512 + tid];
    __syncthreads();

    const int kres = tid >> 7;           // 0..3
    const int c4   = tid & 127;
    const v4f* __restrict__ Wp4 = (const v4f*)W + (size_t)kres * NCOL4 + (size_t)p * 128 + c4;
    v4f a0 = {0.f, 0.f, 0.f, 0.f};
    v4f a1 = {0.f, 0.f, 0.f, 0.f};
#pragma unroll 4
    for (int i = 0; i < 96; ++i) {       // k = 4*i + kres
        v4f w = Wp4[(size_t)i * (4 * NCOL4)];
        a0 += w * cs[4 * i + kres];
        a1 += w * cs[384 + 4 * i + kres];
    }
    red[tid]       = a0;
    red[512 + tid] = a1;
    __syncthreads();
    if (tid < 256) {
        const int b = tid >> 7;
        const int c = tid & 127;
        const int o = b * 512 + c;
        v4f s = red[o] + red[o + 128] + red[o + 256] + red[o + 384];
        s += ((const v4f*)bproj)[(size_t)p * 128 + c];
        ((v4f*)pe)[((size_t)p * 2 + b) * 128 + c] = s;
    }
}

// K2: dec1+dec2 for 4 pe-rows (p pair x both b), one path per block.
// Grid (112, 2): blockIdx.x = pp (p = 2pp+half), blockIdx.y = path (0=A,1=B).
// Writes scaled rows: rows[((p*2+b)*2+path)*1024].
__global__ __launch_bounds__(512) void k_dec(const float* __restrict__ pe,
                                             const float* __restrict__ WA1,
                                             const float* __restrict__ bA1,
                                             const float* __restrict__ WA2,
                                             const float* __restrict__ bA2,
                                             const float* __restrict__ WB1,
                                             const float* __restrict__ bB1,
                                             const float* __restrict__ WB2,
                                             const float* __restrict__ bB2,
                                             const float* __restrict__ scales,
                                             float* __restrict__ rows) {
    const int tid  = threadIdx.x;
    const int pp   = blockIdx.x;         // [0,112)
    const int path = blockIdx.y;         // 0=A, 1=B

    __shared__ float pe_s[4][512];       // local rows: 2half+b
    __shared__ float h_s[4][256];

    // load 4 contiguous pe rows (rho = 4pp .. 4pp+3)
    ((v4f*)pe_s)[tid] = ((const v4f*)pe)[(size_t)pp * 512 + tid];
    __syncthreads();

    const float* __restrict__ W1 = path ? WB1 : WA1;
    const float* __restrict__ b1 = path ? bB1 : bA1;

    // dec1: h = gelu(pe @ W1 + b1) for rows {2half, 2half+1}
    {
        const int half = tid >> 8;
        const int j    = tid & 255;
        float a0 = 0.f, a1 = 0.f;
#pragma unroll 8
        for (int k = 0; k < 512; ++k) {
            float w = W1[k * 256 + j];
            a0 = fmaf(pe_s[2 * half][k], w, a0);
            a1 = fmaf(pe_s[2 * half + 1][k], w, a1);
        }
        float bb = b1[j];
        h_s[2 * half][j]     = gelu_erf(a0 + bb);
        h_s[2 * half + 1][j] = gelu_erf(a1 + bb);
    }
    __syncthreads();

    // dec2: row = (h @ W2 + b2) * scale
    {
        const int half = tid >> 8;
        const int j4   = tid & 255;
        const int p    = 2 * pp + half;
        const v4f* __restrict__ W2 = (const v4f*)(path ? WB2 : WA2);
        const v4f  b2 = ((const v4f*)(path ? bB2 : bA2))[j4];
        const float sc = scales[p * 2 + path];
        v4f a0 = {0.f, 0.f, 0.f, 0.f};
        v4f a1 = {0.f, 0.f, 0.f, 0.f};
#pragma unroll 4
        for (int k = 0; k < 256; ++k) {
            v4f w = W2[k * 256 + j4];
            a0 += h_s[2 * half][k] * w;
            a1 += h_s[2 * half + 1][k] * w;
        }
        v4f* __restrict__ rows4 = (v4f*)rows;
        const size_t rho0 = (size_t)(p * 2) * 2 + path;      // b=0
        rows4[(rho0)     * 256 + j4] = (a0 + b2) * sc;
        rows4[(rho0 + 2) * 256 + j4] = (a1 + b2) * sc;       // b=1: rho+2
    }
}

// K3: balanced scatter. blockIdx.y = b*32+l; blockIdx.x = chunk c in [0,281);
// thread writes f4 indices c*1024 + {tid, 512+tid} of the layer. nt stores.
__global__ __launch_bounds__(512) void k_scatter(const float* __restrict__ rows,
                                                 float* __restrict__ out) {
    const int yl = blockIdx.y;
    const int b  = yl >> 5;
    const int l  = yl & 31;
    const v4f* __restrict__ rows4 = (const v4f*)rows;
    v4f* __restrict__ out4 = (v4f*)out + (size_t)b * 9207808u + (size_t)l * LAYER4;

    const int f0 = blockIdx.x * 1024 + threadIdx.x;
#pragma unroll
    for (int u = 0; u < 2; ++u) {
        const int f = f0 + u * 512;
        // segment lookup: t, segment start, A-piece f4 count
        int t, tstart, Asz = 16384;
        if (f < 106496) {
            if (f < 53248) { if (f < 32768) { t = 0; tstart = 0; }
                             else           { t = 1; tstart = 32768; } }
            else           { if (f < 73728) { t = 2; tstart = 53248; }
                             else           { t = 3; tstart = 73728; } }
        } else {
            if (f < 227328) { if (f < 166912) { t = 4; tstart = 106496; }
                              else            { t = 5; tstart = 166912; } }
            else            { t = 6; tstart = 227328; Asz = 44032; }
        }
        const int local = f - tstart;
        const int p = l * 7 + t;
        const v4f* __restrict__ Arow = rows4 + ((size_t)(p * 2 + b) * 2) * 256;
        v4f v;
        if (local < Asz) {
            // A[r][j]: r = local / (in_d/4); col pattern repeats every 16 f4
            int r = (t == 6) ? (int)(((unsigned)(local >> 6) * 1525u) >> 16)  // /43, exact x<1680
                             : (local >> 10);
            v = Arow[(r << 4) | (local & 15)];
        } else {
            // B[i][j]: i = g>>2, j4 = g&3; source (i%64)*4 + j4; Brow = Arow+256
            int g = local - Asz;
            v = Arow[256 + ((((g >> 2) & 63) << 2) | (g & 3))];
        }
        __builtin_nontemporal_store(v, &out4[f]);
    }
}

extern "C" void kernel_launch(void* const* d_in, const int* in_sizes, int n_in,
                              void* d_out, int out_size, void* d_ws, size_t ws_size,
                              hipStream_t stream) {
    const float* cond   = (const float*)d_in[0];
    const float* Wp     = (const float*)d_in[1];
    const float* bproj  = (const float*)d_in[2];
    const float* WA1    = (const float*)d_in[3];
    const float* bA1    = (const float*)d_in[4];
    const float* WA2    = (const float*)d_in[5];
    const float* bA2    = (const float*)d_in[6];
    const float* WB1    = (const float*)d_in[7];
    const float* bB1    = (const float*)d_in[8];
    const float* WB2    = (const float*)d_in[9];
    const float* bB2    = (const float*)d_in[10];
    const float* scales = (const float*)d_in[11];
    float* out = (float*)d_out;
    float* ws  = (float*)d_ws;

    float* pe   = ws + OFF_PE;
    float* rows = ws + OFF_ROWS;

    hipLaunchKernelGGL(k_gemv,    dim3(224),      dim3(512), 0, stream, cond, Wp, bproj, pe);
    hipLaunchKernelGGL(k_dec,     dim3(112, 2),   dim3(512), 0, stream,
                       pe, WA1, bA1, WA2, bA2, WB1, bB1, WB2, bB2, scales, rows);
    hipLaunchKernelGGL(k_scatter, dim3(281, 64),  dim3(512), 0, stream, rows, out);
}